// Round 1
// baseline (112967.371 us; speedup 1.0000x reference)
//
#include <hip/hip_runtime.h>
#include <cstddef>

#define T_ 1024
#define B_ 64
#define D_ 256
#define L_ 1024
#define DC_ 256
#define H_ 256
#define A_ 256
#define G3 768  // 3*H

__device__ __forceinline__ float fast_tanh(float xx) {
  float e = __expf(2.0f * xx);
  return 1.0f - 2.0f / (e + 1.0f);
}
__device__ __forceinline__ float sigmoidf_(float xx) {
  return 1.0f / (1.0f + __expf(-xx));
}

// ctxT[b][a][l] = sum_d context[b][l][d] * Wc[d][a]
__global__ void ctx_proj_kernel(const float* __restrict__ context,
                                const float* __restrict__ Wc,
                                float* __restrict__ ctxT) {
  __shared__ float cs[4352];  // max(16*256, 256*17)
  const int bid = blockIdx.x;
  const int b = bid >> 6;          // 64 blocks per batch (L/16)
  const int l0 = (bid & 63) << 4;  // 16 l-rows per block
  const int tid = threadIdx.x;
  for (int idx = tid; idx < 16 * DC_; idx += 256) {
    int r = idx >> 8;
    int d = idx & 255;
    cs[r * DC_ + d] = context[((size_t)b * L_ + (l0 + r)) * DC_ + d];
  }
  __syncthreads();
  const int a = tid;
  float acc[16];
#pragma unroll
  for (int r = 0; r < 16; ++r) acc[r] = 0.0f;
  for (int d = 0; d < DC_; ++d) {
    float w = Wc[d * A_ + a];
#pragma unroll
    for (int r = 0; r < 16; ++r) acc[r] += cs[r * DC_ + d] * w;
  }
  __syncthreads();
#pragma unroll
  for (int r = 0; r < 16; ++r) cs[a * 17 + r] = acc[r];
  __syncthreads();
  for (int idx = tid; idx < 16 * A_; idx += 256) {
    int aa = idx >> 4;
    int r = idx & 15;
    ctxT[((size_t)b * A_ + aa) * L_ + l0 + r] = cs[aa * 17 + r];
  }
}

__global__ __launch_bounds__(1024) void encoder_kernel(
    const float* __restrict__ x, const int* __restrict__ lengths,
    const float* __restrict__ context, const int* __restrict__ ctx_lengths,
    const float* __restrict__ Wx, const float* __restrict__ Wh,
    const float* __restrict__ v,
    const float* __restrict__ W_ih, const float* __restrict__ W_hh,
    const float* __restrict__ b_ih, const float* __restrict__ b_hh,
    const float* __restrict__ ctxT, float* __restrict__ out) {
  __shared__ float xt_s[D_];
  __shared__ float h_s[H_];
  __shared__ float c_s[DC_];
  __shared__ float2 qv_s[A_];
  __shared__ float v_s[A_];
  __shared__ float bih_s[G3], bhh_s[G3];
  __shared__ float gi_s[G3], gh_s[G3];
  __shared__ float part[1024];
  __shared__ float p_s[L_];
  __shared__ float wred[16];
  __shared__ float bc[2];

  const int b = blockIdx.x;
  const int tid = threadIdx.x;
  const int len = lengths[b];
  const int clen = ctx_lengths[b];
  const float* ctxTb = ctxT + (size_t)b * A_ * L_;
  const float* ctxb = context + (size_t)b * L_ * DC_;

  if (tid < A_) { v_s[tid] = v[tid]; h_s[tid] = 0.0f; }
  if (tid < G3) { bih_s[tid] = b_ih[tid]; bhh_s[tid] = b_hh[tid]; }
  __syncthreads();

  for (int t = 0; t < len; ++t) {
    if (tid < D_) xt_s[tid] = x[((size_t)t * B_ + b) * D_ + tid];
    __syncthreads();
    // q[a] = xt@Wx + h@Wh  (4-way k-split over 1024 threads)
    {
      const int p = tid >> 8;
      const int a = tid & 255;
      const int k0 = p << 6;
      float acc = 0.0f;
#pragma unroll 4
      for (int k = k0; k < k0 + 64; ++k) acc += xt_s[k] * Wx[k * A_ + a];
#pragma unroll 4
      for (int k = k0; k < k0 + 64; ++k) acc += h_s[k] * Wh[k * A_ + a];
      part[tid] = acc;
    }
    __syncthreads();
    if (tid < A_) {
      float q = part[tid] + part[256 + tid] + part[512 + tid] + part[768 + tid];
      qv_s[tid] = make_float2(q, v_s[tid]);
    }
    __syncthreads();
    // scores: thread tid owns context row l = tid
    float sc = -1e9f;
    if (tid < clen) {
      float acc = 0.0f;
#pragma unroll 8
      for (int a = 0; a < A_; ++a) {
        float e = ctxTb[a * L_ + tid];
        float2 qv = qv_s[a];
        acc += qv.y * fast_tanh(e + qv.x);
      }
      sc = acc;
    }
    // block max
    float mx = sc;
#pragma unroll
    for (int off = 32; off; off >>= 1) mx = fmaxf(mx, __shfl_xor(mx, off));
    if ((tid & 63) == 0) wred[tid >> 6] = mx;
    __syncthreads();
    if (tid < 64) {
      float m2 = (tid < 16) ? wred[tid] : -3e38f;
#pragma unroll
      for (int off = 8; off; off >>= 1) m2 = fmaxf(m2, __shfl_xor(m2, off));
      if (tid == 0) bc[0] = m2;
    }
    __syncthreads();
    const float gmax = bc[0];
    float p = (tid < clen) ? __expf(sc - gmax) : 0.0f;
    p_s[tid] = p;
    float sm = p;
#pragma unroll
    for (int off = 32; off; off >>= 1) sm += __shfl_xor(sm, off);
    if ((tid & 63) == 0) wred[tid >> 6] = sm;
    __syncthreads();
    if (tid < 64) {
      float s2 = (tid < 16) ? wred[tid] : 0.0f;
#pragma unroll
      for (int off = 8; off; off >>= 1) s2 += __shfl_xor(s2, off);
      if (tid == 0) bc[1] = s2;
    }
    __syncthreads();
    const float inv_sum = 1.0f / bc[1];
    // c[d] = (1/sum) * sum_l p[l]*context[b][l][d]  (4-way l-split)
    {
      const int pg = tid >> 8;
      const int d = tid & 255;
      const int l0 = pg << 8;
      const int l1 = min(l0 + 256, clen);
      float acc = 0.0f;
#pragma unroll 4
      for (int ll = l0; ll < l1; ++ll) acc += p_s[ll] * ctxb[(size_t)ll * DC_ + d];
      part[tid] = acc;
    }
    __syncthreads();
    if (tid < DC_) {
      c_s[tid] = (part[tid] + part[256 + tid] + part[512 + tid] + part[768 + tid]) * inv_sum;
    }
    __syncthreads();
    // GRU gates
    if (tid < G3) {
      const int j = tid;
      float gi = bih_s[j];
      float gh = bhh_s[j];
#pragma unroll 4
      for (int k = 0; k < D_; ++k) gi += xt_s[k] * W_ih[k * G3 + j];
#pragma unroll 4
      for (int k = 0; k < DC_; ++k) gi += c_s[k] * W_ih[(D_ + k) * G3 + j];
#pragma unroll 4
      for (int k = 0; k < H_; ++k) gh += h_s[k] * W_hh[k * G3 + j];
      gi_s[j] = gi;
      gh_s[j] = gh;
    }
    __syncthreads();
    if (tid < H_) {
      float r = sigmoidf_(gi_s[tid] + gh_s[tid]);
      float u = sigmoidf_(gi_s[256 + tid] + gh_s[256 + tid]);
      float n = fast_tanh(gi_s[512 + tid] + r * gh_s[512 + tid]);
      float hn = u * h_s[tid] + (1.0f - u) * n;
      h_s[tid] = hn;
      out[((size_t)t * B_ + b) * H_ + tid] = hn;
    }
    __syncthreads();
  }
  // zero-fill masked timesteps
  const int tail = (T_ - len) * H_;
  for (int idx = tid; idx < tail; idx += 1024) {
    int tt = len + (idx >> 8);
    int i = idx & 255;
    out[((size_t)tt * B_ + b) * H_ + i] = 0.0f;
  }
  // h_final
  if (tid < H_) out[(size_t)T_ * B_ * H_ + b * H_ + tid] = h_s[tid];
}

extern "C" void kernel_launch(void* const* d_in, const int* in_sizes, int n_in,
                              void* d_out, int out_size, void* d_ws, size_t ws_size,
                              hipStream_t stream) {
  const float* x = (const float*)d_in[0];
  const int* lengths = (const int*)d_in[1];
  const float* context = (const float*)d_in[2];
  const int* ctx_lengths = (const int*)d_in[3];
  const float* Wc = (const float*)d_in[4];
  const float* Wx = (const float*)d_in[5];
  const float* Wh = (const float*)d_in[6];
  const float* v = (const float*)d_in[7];
  const float* W_ih = (const float*)d_in[8];
  const float* W_hh = (const float*)d_in[9];
  const float* b_ih = (const float*)d_in[10];
  const float* b_hh = (const float*)d_in[11];
  float* out = (float*)d_out;
  float* ctxT = (float*)d_ws;  // B*A*L floats = 64 MB

  hipLaunchKernelGGL(ctx_proj_kernel, dim3(B_ * (L_ / 16)), dim3(256), 0, stream,
                     context, Wc, ctxT);
  hipLaunchKernelGGL(encoder_kernel, dim3(B_), dim3(1024), 0, stream,
                     x, lengths, context, ctx_lengths, Wx, Wh, v,
                     W_ih, W_hh, b_ih, b_hh, ctxT, out);
}

// Round 2
// 110841.724 us; speedup vs baseline: 1.0192x; 1.0192x over previous
//
#include <hip/hip_runtime.h>
#include <cstddef>

#define T_ 1024
#define B_ 64
#define D_ 256
#define L_ 1024
#define DC_ 256
#define H_ 256
#define A_ 256
#define G3 768  // 3*H

__device__ __forceinline__ float fast_tanh(float xx) {
  float e = __expf(2.0f * xx);
  return 1.0f - 2.0f / (e + 1.0f);
}
__device__ __forceinline__ float sigmoidf_(float xx) {
  return 1.0f / (1.0f + __expf(-xx));
}

// ctxT[b][a][l] = sum_d context[b][l][d] * Wc[d][a]
__global__ void ctx_proj_kernel(const float* __restrict__ context,
                                const float* __restrict__ Wc,
                                float* __restrict__ ctxT) {
  __shared__ float cs[4352];  // max(16*256, 256*17)
  const int bid = blockIdx.x;
  const int b = bid >> 6;          // 64 blocks per batch (L/16)
  const int l0 = (bid & 63) << 4;  // 16 l-rows per block
  const int tid = threadIdx.x;
  for (int idx = tid; idx < 16 * DC_; idx += 256) {
    int r = idx >> 8;
    int d = idx & 255;
    cs[r * DC_ + d] = context[((size_t)b * L_ + (l0 + r)) * DC_ + d];
  }
  __syncthreads();
  const int a = tid;
  float acc[16];
#pragma unroll
  for (int r = 0; r < 16; ++r) acc[r] = 0.0f;
  for (int d = 0; d < DC_; ++d) {
    float w = Wc[d * A_ + a];
#pragma unroll
    for (int r = 0; r < 16; ++r) acc[r] += cs[r * DC_ + d] * w;
  }
  __syncthreads();
#pragma unroll
  for (int r = 0; r < 16; ++r) cs[a * 17 + r] = acc[r];
  __syncthreads();
  for (int idx = tid; idx < 16 * A_; idx += 256) {
    int aa = idx >> 4;
    int r = idx & 15;
    ctxT[((size_t)b * A_ + aa) * L_ + l0 + r] = cs[aa * 17 + r];
  }
}

__global__ __launch_bounds__(1024) void encoder_kernel(
    const float* __restrict__ x, const int* __restrict__ lengths,
    const float* __restrict__ context, const int* __restrict__ ctx_lengths,
    const float* __restrict__ Wx, const float* __restrict__ Wh,
    const float* __restrict__ v,
    const float* __restrict__ W_ih, const float* __restrict__ W_hh,
    const float* __restrict__ b_ih, const float* __restrict__ b_hh,
    const float* __restrict__ ctxT, float* __restrict__ out) {
  __shared__ float xt_s[D_];
  __shared__ float h_s[H_];
  __shared__ float c_s[DC_];
  __shared__ float2 qv_s[A_];     // (.x = q_t[a], .y = v[a])
  __shared__ float bih_s[G3], bhh_s[G3];
  __shared__ float gi_s[G3], gh_s[G3];
  __shared__ float4 part4[1024];      // 16 KB shared reduce buffer
  __shared__ float4 part4b[4 * 192];  // 12 KB (GRU gh partials)
  __shared__ float pv_s[L_];          // unnormalized softmax weights
  __shared__ float wsum[4];

  const int b = blockIdx.x;
  const int tid = threadIdx.x;
  const int len = lengths[b];
  const int clen = ctx_lengths[b];
  const float* ctxTb = ctxT + (size_t)b * A_ * L_;
  const float* ctxb = context + (size_t)b * L_ * DC_;

  const int p4 = tid >> 8, i256 = tid & 255;   // 4-way split
  const int p16 = tid >> 6, i64 = tid & 63;    // 16-way split

  if (tid < A_) { qv_s[tid] = make_float2(0.0f, v[tid]); h_s[tid] = 0.0f; }
  if (tid < G3) { bih_s[tid] = b_ih[tid]; bhh_s[tid] = b_hh[tid]; }

  for (int t = 0; t < len; ++t) {
    if (tid < 64) {
      *(float4*)&xt_s[tid * 4] =
          *(const float4*)&x[((size_t)t * B_ + b) * D_ + tid * 4];
    }
    __syncthreads();

    // ---- q[a] = xt@Wx + h@Wh : thread (p16,i64) -> cols 4*i64.., k in 16-way split
    {
      const int a0 = i64 * 4, k0 = p16 * 16;
      float4 acc = make_float4(0.f, 0.f, 0.f, 0.f);
#pragma unroll
      for (int k = k0; k < k0 + 16; ++k) {
        float xv = xt_s[k];
        float4 w = *(const float4*)&Wx[(size_t)k * A_ + a0];
        acc.x += xv * w.x; acc.y += xv * w.y; acc.z += xv * w.z; acc.w += xv * w.w;
      }
#pragma unroll
      for (int k = k0; k < k0 + 16; ++k) {
        float hv = h_s[k];
        float4 w = *(const float4*)&Wh[(size_t)k * A_ + a0];
        acc.x += hv * w.x; acc.y += hv * w.y; acc.z += hv * w.z; acc.w += hv * w.w;
      }
      part4[tid] = acc;  // idx = p16*64 + i64 = tid
    }
    __syncthreads();
    if (tid < A_) {
      const float* pf = (const float*)part4;
      float q = 0.f;
#pragma unroll
      for (int p = 0; p < 16; ++p) q += pf[p * 256 + tid];
      qv_s[tid].x = q;
    }
    __syncthreads();

    // ---- scores: thread (p4,i256) -> l = 4*i256.., a in [64*p4, 64*p4+64)
    {
      const int l0 = i256 * 4;
      float4 acc = make_float4(0.f, 0.f, 0.f, 0.f);
      if (l0 < clen) {
        const float* basep = ctxTb + (size_t)(p4 * 64) * L_ + l0;
#pragma unroll 8
        for (int aa = 0; aa < 64; ++aa) {
          float4 e = *(const float4*)(basep + (size_t)aa * L_);
          float2 qv = qv_s[p4 * 64 + aa];
          acc.x += qv.y * fast_tanh(e.x + qv.x);
          acc.y += qv.y * fast_tanh(e.y + qv.x);
          acc.z += qv.y * fast_tanh(e.z + qv.x);
          acc.w += qv.y * fast_tanh(e.w + qv.x);
        }
      }
      part4[p4 * 256 + i256] = acc;
    }
    __syncthreads();
    // ---- finalize scores -> exp (no max shift: |score| <= ||v||_1 ~ 13), fused sum
    if (tid < 256) {
      float4 a0 = part4[tid], a1 = part4[256 + tid];
      float4 a2 = part4[512 + tid], a3 = part4[768 + tid];
      const int l0 = tid * 4;
      float e0 = (l0     < clen) ? __expf(a0.x + a1.x + a2.x + a3.x) : 0.f;
      float e1 = (l0 + 1 < clen) ? __expf(a0.y + a1.y + a2.y + a3.y) : 0.f;
      float e2 = (l0 + 2 < clen) ? __expf(a0.z + a1.z + a2.z + a3.z) : 0.f;
      float e3 = (l0 + 3 < clen) ? __expf(a0.w + a1.w + a2.w + a3.w) : 0.f;
      *(float4*)&pv_s[l0] = make_float4(e0, e1, e2, e3);
      float s = e0 + e1 + e2 + e3;
#pragma unroll
      for (int off = 32; off; off >>= 1) s += __shfl_xor(s, off);
      if ((tid & 63) == 0) wsum[tid >> 6] = s;
    }
    __syncthreads();
    const float inv_sum = 1.0f / (wsum[0] + wsum[1] + wsum[2] + wsum[3]);

    // ---- c[d] = (1/sum) sum_l pv[l]*context[l][d] : thread (p16,i64) -> d=4*i64..
    {
      const int d0 = i64 * 4;
      const int l0 = p16 * 64, l1 = min(l0 + 64, clen);
      float4 acc = make_float4(0.f, 0.f, 0.f, 0.f);
      for (int l = l0; l < l1; ++l) {
        float pv = pv_s[l];
        float4 cv = *(const float4*)&ctxb[(size_t)l * DC_ + d0];
        acc.x += pv * cv.x; acc.y += pv * cv.y; acc.z += pv * cv.z; acc.w += pv * cv.w;
      }
      part4[tid] = acc;  // idx = p16*64 + i64 = tid
    }
    __syncthreads();
    if (tid < DC_) {
      const float* pf = (const float*)part4;
      float cacc = 0.f;
#pragma unroll
      for (int p = 0; p < 16; ++p) cacc += pf[p * 256 + tid];
      c_s[tid] = cacc * inv_sum;
    }
    __syncthreads();

    // ---- GRU partials: thread (p4, jg=i256<192) -> cols j=4*jg.., k 4-way split
    if (i256 < 192) {
      const int j0 = i256 * 4;
      float4 ai = make_float4(0.f, 0.f, 0.f, 0.f);
      float4 ah = make_float4(0.f, 0.f, 0.f, 0.f);
      if (p4 < 2) {  // k-quarters 0,1: xt rows of W_ih
        const int k0 = p4 * 128;
#pragma unroll 4
        for (int k = k0; k < k0 + 128; ++k) {
          float zk = xt_s[k];
          float4 w = *(const float4*)&W_ih[(size_t)k * G3 + j0];
          ai.x += zk * w.x; ai.y += zk * w.y; ai.z += zk * w.z; ai.w += zk * w.w;
        }
      } else {       // k-quarters 2,3: c rows of W_ih
        const int k0 = (p4 - 2) * 128;
#pragma unroll 4
        for (int k = k0; k < k0 + 128; ++k) {
          float zk = c_s[k];
          float4 w = *(const float4*)&W_ih[(size_t)(k + 256) * G3 + j0];
          ai.x += zk * w.x; ai.y += zk * w.y; ai.z += zk * w.z; ai.w += zk * w.w;
        }
      }
      {
        const int k0 = p4 * 64;
#pragma unroll 4
        for (int k = k0; k < k0 + 64; ++k) {
          float hv = h_s[k];
          float4 w = *(const float4*)&W_hh[(size_t)k * G3 + j0];
          ah.x += hv * w.x; ah.y += hv * w.y; ah.z += hv * w.z; ah.w += hv * w.w;
        }
      }
      part4[p4 * 256 + i256] = ai;
      part4b[p4 * 192 + i256] = ah;
    }
    __syncthreads();
    if (tid < G3) {
      const float* pf = (const float*)part4;
      const float* pfb = (const float*)part4b;
      float gi = bih_s[tid], gh = bhh_s[tid];
#pragma unroll
      for (int p = 0; p < 4; ++p) {
        gi += pf[p * 1024 + tid];   // (p*256+jg)*4+cmp = p*1024+tid
        gh += pfb[p * 768 + tid];   // (p*192+jg)*4+cmp = p*768+tid
      }
      gi_s[tid] = gi; gh_s[tid] = gh;
    }
    __syncthreads();
    if (tid < H_) {
      float r = sigmoidf_(gi_s[tid] + gh_s[tid]);
      float u = sigmoidf_(gi_s[256 + tid] + gh_s[256 + tid]);
      float n = fast_tanh(gi_s[512 + tid] + r * gh_s[512 + tid]);
      float hn = u * h_s[tid] + (1.0f - u) * n;
      h_s[tid] = hn;
      out[((size_t)t * B_ + b) * H_ + tid] = hn;
    }
    __syncthreads();
  }
  // zero-fill masked timesteps
  const int tail = (T_ - len) * H_;
  for (int idx = tid; idx < tail; idx += 1024) {
    int tt = len + (idx >> 8);
    out[((size_t)tt * B_ + b) * H_ + (idx & 255)] = 0.0f;
  }
  // h_final
  if (tid < H_) out[(size_t)T_ * B_ * H_ + (size_t)b * H_ + tid] = h_s[tid];
}

extern "C" void kernel_launch(void* const* d_in, const int* in_sizes, int n_in,
                              void* d_out, int out_size, void* d_ws, size_t ws_size,
                              hipStream_t stream) {
  const float* x = (const float*)d_in[0];
  const int* lengths = (const int*)d_in[1];
  const float* context = (const float*)d_in[2];
  const int* ctx_lengths = (const int*)d_in[3];
  const float* Wc = (const float*)d_in[4];
  const float* Wx = (const float*)d_in[5];
  const float* Wh = (const float*)d_in[6];
  const float* v = (const float*)d_in[7];
  const float* W_ih = (const float*)d_in[8];
  const float* W_hh = (const float*)d_in[9];
  const float* b_ih = (const float*)d_in[10];
  const float* b_hh = (const float*)d_in[11];
  float* out = (float*)d_out;
  float* ctxT = (float*)d_ws;  // B*A*L floats = 64 MB

  hipLaunchKernelGGL(ctx_proj_kernel, dim3(B_ * (L_ / 16)), dim3(256), 0, stream,
                     context, Wc, ctxT);
  hipLaunchKernelGGL(encoder_kernel, dim3(B_), dim3(1024), 0, stream,
                     x, lengths, context, ctx_lengths, Wx, Wh, v,
                     W_ih, W_hh, b_ih, b_hh, ctxT, out);
}